// Round 4
// baseline (814.827 us; speedup 1.0000x reference)
//
#include <hip/hip_runtime.h>

typedef __attribute__((ext_vector_type(8))) _Float16 f16x8;
typedef __attribute__((ext_vector_type(2))) __fp16   fp16x2;  // cvt_pkrtz return type
typedef __attribute__((ext_vector_type(4))) float    f32x4;

#define TT 16384
#define KD 1024
#define ND 3072
#define NE 16

#define BM 256
#define BN 256
#define BK 64
#define NSTEP (KD / BK)   // 16
#define NTHREADS 512
#define ROWB (BK * 2)     // 128 bytes per LDS row (fp16)

// lgkmcnt(0) + raw barrier: LDS hazards fenced, but vmcnt (global->reg loads)
// deliberately NOT drained -- loads stay in flight across the barrier (T4).
#define LGKM0_BAR() do {                                        \
    asm volatile("s_waitcnt lgkmcnt(0)" ::: "memory");          \
    __builtin_amdgcn_s_barrier();                               \
} while (0)

// XOR swizzle: spreads same-column reads of 8 consecutive rows across banks.
__device__ __forceinline__ int swz(int row, int kbyte) {
    return row * ROWB + (kbyte ^ ((row & 7) << 4));
}

__device__ __forceinline__ int find_expert(const void* cntp, int row0) {
    // JAX default config demotes int64 -> int32; detect which layout we got.
    const int* w = (const int*)cntp;
    int oddsum = 0;
    #pragma unroll
    for (int i = 1; i < 16; i += 2) oddsum |= w[i];
    int e = 0;
    long long cum = 0;
    if (oddsum == 0) {  // int64 counts (high words all zero)
        const long long* c = (const long long*)cntp;
        #pragma unroll
        for (int i = 0; i < NE; ++i) { if ((long long)row0 >= cum) e = i; cum += c[i]; }
    } else {            // int32 counts
        #pragma unroll
        for (int i = 0; i < NE; ++i) { if ((long long)row0 >= cum) e = i; cum += w[i]; }
    }
    return e;
}

__launch_bounds__(NTHREADS, 2)
__global__ void grouped_gemm_f16(const float* __restrict__ A,
                                 const void* __restrict__ cnt,
                                 const float* __restrict__ W,
                                 const float* __restrict__ bias,
                                 float* __restrict__ Y) {
    // [dbuf][A/B][256 rows x 128B] = 128 KiB
    __shared__ __align__(16) char ldsbuf[2][2][BM * ROWB];
    char* const A0 = ldsbuf[0][0]; char* const B0 = ldsbuf[0][1];
    char* const A1 = ldsbuf[1][0]; char* const B1 = ldsbuf[1][1];

    // T1: bijective XCD-aware swizzle (768 % 8 == 0)
    const int nwg = gridDim.x;
    const int bid0 = blockIdx.x;
    const int wgid = (bid0 & 7) * (nwg >> 3) + (bid0 >> 3);

    const int mt = wgid / (ND / BN);
    const int nt = wgid % (ND / BN);
    const int row0 = mt * BM;
    const int col0 = nt * BN;

    const int e = find_expert(cnt, row0);
    const float* We = W + (size_t)e * ND * KD;

    const int tid = threadIdx.x;
    const int lane = tid & 63;
    const int w = tid >> 6;   // wave 0..7
    const int wr = w >> 2;    // 0..1 (M half, 128 rows)
    const int wc = w & 3;     // 0..3 (N quarter, 64 cols)
    const int lr = lane & 15;
    const int lk = lane >> 4;

    // Staging: A tile and B tile each = 256 rows x 64 k fp32 = 2048 chunks of
    // 8 floats; 512 threads x 4 chunks. tid walks k-first (coalesced).
    int soff[4];
    size_t aoff[4], boff[4];
    #pragma unroll
    for (int c = 0; c < 4; ++c) {
        int q = c * NTHREADS + tid;
        int r = q >> 3;
        int kb = (q & 7) * 8;
        soff[c] = swz(r, kb * 2);
        aoff[c] = (size_t)(row0 + r) * KD + kb;
        boff[c] = (size_t)(col0 + r) * KD + kb;
    }

    // Two staging register sets (2-deep prefetch). Static indexing only.
    f32x4 ra0[4][2], rb0[4][2];
    f32x4 ra1[4][2], rb1[4][2];

    auto loadS0 = [&](int ks) {
        const int k0 = ks * BK;
        #pragma unroll
        for (int c = 0; c < 4; ++c) {
            const float* ap = A + aoff[c] + k0;
            ra0[c][0] = *(const f32x4*)ap;
            ra0[c][1] = *(const f32x4*)(ap + 4);
            const float* bp = We + boff[c] + k0;
            rb0[c][0] = *(const f32x4*)bp;
            rb0[c][1] = *(const f32x4*)(bp + 4);
        }
    };
    auto loadS1 = [&](int ks) {
        const int k0 = ks * BK;
        #pragma unroll
        for (int c = 0; c < 4; ++c) {
            const float* ap = A + aoff[c] + k0;
            ra1[c][0] = *(const f32x4*)ap;
            ra1[c][1] = *(const f32x4*)(ap + 4);
            const float* bp = We + boff[c] + k0;
            rb1[c][0] = *(const f32x4*)bp;
            rb1[c][1] = *(const f32x4*)(bp + 4);
        }
    };

    auto writeS0 = [&](char* dA, char* dB) {
        #pragma unroll
        for (int c = 0; c < 4; ++c) {
            union { f16x8 v; fp16x2 h[4]; } ua, ub;
            ua.h[0] = __builtin_amdgcn_cvt_pkrtz(ra0[c][0][0], ra0[c][0][1]);
            ua.h[1] = __builtin_amdgcn_cvt_pkrtz(ra0[c][0][2], ra0[c][0][3]);
            ua.h[2] = __builtin_amdgcn_cvt_pkrtz(ra0[c][1][0], ra0[c][1][1]);
            ua.h[3] = __builtin_amdgcn_cvt_pkrtz(ra0[c][1][2], ra0[c][1][3]);
            ub.h[0] = __builtin_amdgcn_cvt_pkrtz(rb0[c][0][0], rb0[c][0][1]);
            ub.h[1] = __builtin_amdgcn_cvt_pkrtz(rb0[c][0][2], rb0[c][0][3]);
            ub.h[2] = __builtin_amdgcn_cvt_pkrtz(rb0[c][1][0], rb0[c][1][1]);
            ub.h[3] = __builtin_amdgcn_cvt_pkrtz(rb0[c][1][2], rb0[c][1][3]);
            *(f16x8*)&dA[soff[c]] = ua.v;
            *(f16x8*)&dB[soff[c]] = ub.v;
        }
    };
    auto writeS1 = [&](char* dA, char* dB) {
        #pragma unroll
        for (int c = 0; c < 4; ++c) {
            union { f16x8 v; fp16x2 h[4]; } ua, ub;
            ua.h[0] = __builtin_amdgcn_cvt_pkrtz(ra1[c][0][0], ra1[c][0][1]);
            ua.h[1] = __builtin_amdgcn_cvt_pkrtz(ra1[c][0][2], ra1[c][0][3]);
            ua.h[2] = __builtin_amdgcn_cvt_pkrtz(ra1[c][1][0], ra1[c][1][1]);
            ua.h[3] = __builtin_amdgcn_cvt_pkrtz(ra1[c][1][2], ra1[c][1][3]);
            ub.h[0] = __builtin_amdgcn_cvt_pkrtz(rb1[c][0][0], rb1[c][0][1]);
            ub.h[1] = __builtin_amdgcn_cvt_pkrtz(rb1[c][0][2], rb1[c][0][3]);
            ub.h[2] = __builtin_amdgcn_cvt_pkrtz(rb1[c][1][0], rb1[c][1][1]);
            ub.h[3] = __builtin_amdgcn_cvt_pkrtz(rb1[c][1][2], rb1[c][1][3]);
            *(f16x8*)&dA[soff[c]] = ua.v;
            *(f16x8*)&dB[soff[c]] = ub.v;
        }
    };

    f32x4 acc[8][4] = {};   // per-wave 128x64 output

    auto compute = [&](const char* As, const char* Bs) {
        #pragma unroll
        for (int kk = 0; kk < 2; ++kk) {          // two K=32 sub-steps
            f16x8 af[8], bf[4];
            #pragma unroll
            for (int m = 0; m < 8; ++m) {
                int r = wr * 128 + m * 16 + lr;
                af[m] = *(const f16x8*)&As[swz(r, kk * 64 + lk * 16)];
            }
            #pragma unroll
            for (int n = 0; n < 4; ++n) {
                int r = wc * 64 + n * 16 + lr;
                bf[n] = *(const f16x8*)&Bs[swz(r, kk * 64 + lk * 16)];
            }
            #pragma unroll
            for (int m = 0; m < 8; ++m)
                #pragma unroll
                for (int n = 0; n < 4; ++n)
                    acc[m][n] = __builtin_amdgcn_mfma_f32_16x16x32_f16(
                        af[m], bf[n], acc[m][n], 0, 0, 0);
        }
    };

    // ---- Prologue: t0 staged; t1,t2 in flight ----
    loadS0(0);
    writeS0(A0, B0);            // compiler inserts counted vmcnt for S0 here
    loadS0(1);
    loadS1(2);
    LGKM0_BAR();

    // ---- Main loop: 2 K-steps per iteration (buffer parity compile-time).
    // At each write, the consumed set's loads are ~2 steps old -> the
    // compiler's dataflow wait is vmcnt(16) (other set still in flight),
    // never a drain. Loads cross barriers untouched.
    for (int it = 0; it < 6; ++it) {
        compute(A0, B0);            // tile 2it
        writeS0(A1, B1);            // tile 2it+1
        loadS0(2 * it + 3);
        LGKM0_BAR();
        compute(A1, B1);            // tile 2it+1
        writeS1(A0, B0);            // tile 2it+2
        loadS1(2 * it + 4);
        LGKM0_BAR();
    }
    // ---- Peeled it=6 ----
    compute(A0, B0);    // t12
    writeS0(A1, B1);    // t13
    loadS0(15);
    LGKM0_BAR();
    compute(A1, B1);    // t13
    writeS1(A0, B0);    // t14
    LGKM0_BAR();
    // ---- Tail ----
    compute(A0, B0);    // t14
    writeS0(A1, B1);    // t15
    LGKM0_BAR();
    compute(A1, B1);    // t15

    // Epilogue: C/D layout col = lane&15, row = (lane>>4)*4 + j
    const int cb = col0 + wc * 64;
    const int rb0_ = row0 + wr * 128;
    float bv[4];
    #pragma unroll
    for (int n = 0; n < 4; ++n) bv[n] = bias[(size_t)e * ND + cb + n * 16 + lr];
    #pragma unroll
    for (int m = 0; m < 8; ++m) {
        #pragma unroll
        for (int j = 0; j < 4; ++j) {
            int r = rb0_ + m * 16 + lk * 4 + j;
            float* yp = Y + (size_t)r * ND + cb + lr;
            #pragma unroll
            for (int n = 0; n < 4; ++n)
                yp[n * 16] = acc[m][n][j] + bv[n];
        }
    }
}

extern "C" void kernel_launch(void* const* d_in, const int* in_sizes, int n_in,
                              void* d_out, int out_size, void* d_ws, size_t ws_size,
                              hipStream_t stream) {
    const float* inp  = (const float*)d_in[0];
    const void*  cnt  = d_in[1];               // int32 or int64, detected in-kernel
    const float* wgt  = (const float*)d_in[2];
    const float* bias = (const float*)d_in[3];
    float* out = (float*)d_out;

    dim3 grid((TT / BM) * (ND / BN));          // 64 * 12 = 768 blocks
    dim3 block(NTHREADS);
    grouped_gemm_f16<<<grid, block, 0, stream>>>(inp, cnt, wgt, bias, out);
}

// Round 5
// 335.674 us; speedup vs baseline: 2.4274x; 2.4274x over previous
//
#include <hip/hip_runtime.h>

typedef __attribute__((ext_vector_type(8))) _Float16 f16x8;
typedef __attribute__((ext_vector_type(2))) __fp16   fp16x2;  // cvt_pkrtz return type
typedef __attribute__((ext_vector_type(4))) float    f32x4;

#define TT 16384
#define KD 1024
#define ND 3072
#define NE 16

#define BM 128
#define BN 128
#define BK 64
#define NSTEP (KD / BK)   // 16
#define NTHREADS 256
#define ROWB (BK * 2)     // 128 bytes per LDS row (fp16)

// XOR swizzle: conflict-free ds_read_b128 column access on 128B rows (m201).
__device__ __forceinline__ int swz(int row, int kbyte) {
    return row * ROWB + (kbyte ^ ((row & 7) << 4));
}

__device__ __forceinline__ int find_expert(const void* cntp, int row0) {
    // JAX default config demotes int64 -> int32; detect which layout we got.
    const int* w = (const int*)cntp;
    int oddsum = 0;
    #pragma unroll
    for (int i = 1; i < 16; i += 2) oddsum |= w[i];
    int e = 0;
    long long cum = 0;
    if (oddsum == 0) {  // int64 counts (high words all zero)
        const long long* c = (const long long*)cntp;
        #pragma unroll
        for (int i = 0; i < NE; ++i) { if ((long long)row0 >= cum) e = i; cum += c[i]; }
    } else {            // int32 counts
        #pragma unroll
        for (int i = 0; i < NE; ++i) { if ((long long)row0 >= cum) e = i; cum += w[i]; }
    }
    return e;
}

// 3 blocks/CU target: 12 waves/CU, unsynchronized across blocks so one
// block's staging-arrival stall is hidden by the other blocks' compute.
__launch_bounds__(NTHREADS, 3)
__global__ void grouped_gemm_f16(const float* __restrict__ A,
                                 const void* __restrict__ cnt,
                                 const float* __restrict__ W,
                                 const float* __restrict__ bias,
                                 float* __restrict__ Y) {
    // Single-buffered: 2 x 16 KiB = 32 KiB -> LDS allows 5 blocks/CU (regs bind at 3).
    __shared__ __align__(16) char As[BM * ROWB];
    __shared__ __align__(16) char Bs[BN * ROWB];

    // T1: bijective XCD-aware swizzle (3072 % 8 == 0)
    const int nwg = gridDim.x;          // 3072
    const int bid0 = blockIdx.x;
    const int wgid = (bid0 & 7) * (nwg >> 3) + (bid0 >> 3);

    const int mt = wgid / (ND / BN);
    const int nt = wgid % (ND / BN);
    const int row0 = mt * BM;
    const int col0 = nt * BN;

    const int e = find_expert(cnt, row0);
    const float* We = W + (size_t)e * ND * KD;

    const int tid = threadIdx.x;
    const int lane = tid & 63;
    const int w = tid >> 6;   // wave 0..3
    const int wr = w >> 1;    // 0..1 (M half, 64 rows)
    const int wc = w & 1;     // 0..1 (N half, 64 cols)
    const int lr = lane & 15;
    const int lk = lane >> 4;

    // Staging: A tile and B tile each = 128 rows x 64 k fp32 = 1024 chunks of
    // 8 floats; 256 threads x 4 chunks each. Same (r,kb) pattern for A and B.
    int soff[4], aoff[4], boff[4];
    #pragma unroll
    for (int c = 0; c < 4; ++c) {
        int q = c * NTHREADS + tid;
        int r = q >> 3;              // 0..127
        int kb = (q & 7) * 8;        // fp32 element offset in K
        soff[c] = swz(r, kb * 2);
        aoff[c] = (row0 + r) * KD + kb;   // fits int (16.8M max)
        boff[c] = (col0 + r) * KD + kb;   // into We (3.1M max)
    }

    f32x4 ra[4][2], rb[4][2];   // one K-step of staging in flight (64 VGPRs)

    auto load_regs = [&](int ks) {
        const int k0 = ks * BK;
        #pragma unroll
        for (int c = 0; c < 4; ++c) {
            const float* ap = A + aoff[c] + k0;
            ra[c][0] = *(const f32x4*)ap;
            ra[c][1] = *(const f32x4*)(ap + 4);
            const float* bp = We + boff[c] + k0;
            rb[c][0] = *(const f32x4*)bp;
            rb[c][1] = *(const f32x4*)(bp + 4);
        }
    };

    auto write_lds = [&]() {
        #pragma unroll
        for (int c = 0; c < 4; ++c) {
            union { f16x8 v; fp16x2 h[4]; } ua, ub;
            ua.h[0] = __builtin_amdgcn_cvt_pkrtz(ra[c][0][0], ra[c][0][1]);
            ua.h[1] = __builtin_amdgcn_cvt_pkrtz(ra[c][0][2], ra[c][0][3]);
            ua.h[2] = __builtin_amdgcn_cvt_pkrtz(ra[c][1][0], ra[c][1][1]);
            ua.h[3] = __builtin_amdgcn_cvt_pkrtz(ra[c][1][2], ra[c][1][3]);
            ub.h[0] = __builtin_amdgcn_cvt_pkrtz(rb[c][0][0], rb[c][0][1]);
            ub.h[1] = __builtin_amdgcn_cvt_pkrtz(rb[c][0][2], rb[c][0][3]);
            ub.h[2] = __builtin_amdgcn_cvt_pkrtz(rb[c][1][0], rb[c][1][1]);
            ub.h[3] = __builtin_amdgcn_cvt_pkrtz(rb[c][1][2], rb[c][1][3]);
            *(f16x8*)&As[soff[c]] = ua.v;
            *(f16x8*)&Bs[soff[c]] = ub.v;
        }
    };

    f32x4 acc[4][4] = {};   // per-wave 64x64 output (64 regs, AGPR-side)

    // Prologue: stage tile 0 (vmcnt wait is internal to write_lds's data deps)
    load_regs(0);
    write_lds();

    for (int ks = 0; ks < NSTEP; ++ks) {
        __syncthreads();                       // staged tile visible
        if (ks + 1 < NSTEP) load_regs(ks + 1); // issue next loads early

        #pragma unroll
        for (int kk = 0; kk < 2; ++kk) {       // two K=32 sub-steps
            f16x8 af[4], bf[4];
            #pragma unroll
            for (int m = 0; m < 4; ++m) {
                int r = wr * 64 + m * 16 + lr;
                af[m] = *(const f16x8*)&As[swz(r, kk * 64 + lk * 16)];
            }
            #pragma unroll
            for (int n = 0; n < 4; ++n) {
                int r = wc * 64 + n * 16 + lr;
                bf[n] = *(const f16x8*)&Bs[swz(r, kk * 64 + lk * 16)];
            }
            __builtin_amdgcn_s_setprio(1);
            #pragma unroll
            for (int m = 0; m < 4; ++m)
                #pragma unroll
                for (int n = 0; n < 4; ++n)
                    acc[m][n] = __builtin_amdgcn_mfma_f32_16x16x32_f16(
                        af[m], bf[n], acc[m][n], 0, 0, 0);
            __builtin_amdgcn_s_setprio(0);
        }

        __syncthreads();                       // all reads done (drains vmcnt;
                                               // covered by other blocks on CU)
        if (ks + 1 < NSTEP) write_lds();
    }

    // Epilogue: C/D layout col = lane&15, row = (lane>>4)*4 + j
    const int cb = col0 + wc * 64;
    const int rb0_ = row0 + wr * 64;
    float bv[4];
    #pragma unroll
    for (int n = 0; n < 4; ++n) bv[n] = bias[(size_t)e * ND + cb + n * 16 + lr];
    #pragma unroll
    for (int m = 0; m < 4; ++m) {
        #pragma unroll
        for (int j = 0; j < 4; ++j) {
            int r = rb0_ + m * 16 + lk * 4 + j;
            float* yp = Y + (size_t)r * ND + cb + lr;
            #pragma unroll
            for (int n = 0; n < 4; ++n)
                yp[n * 16] = acc[m][n][j] + bv[n];
        }
    }
}

extern "C" void kernel_launch(void* const* d_in, const int* in_sizes, int n_in,
                              void* d_out, int out_size, void* d_ws, size_t ws_size,
                              hipStream_t stream) {
    const float* inp  = (const float*)d_in[0];
    const void*  cnt  = d_in[1];               // int32 or int64, detected in-kernel
    const float* wgt  = (const float*)d_in[2];
    const float* bias = (const float*)d_in[3];
    float* out = (float*)d_out;

    dim3 grid((TT / BM) * (ND / BN));          // 128 * 24 = 3072 blocks
    dim3 block(NTHREADS);
    grouped_gemm_f16<<<grid, block, 0, stream>>>(inp, cnt, wgt, bias, out);
}

// Round 6
// 205.914 us; speedup vs baseline: 3.9571x; 1.6302x over previous
//
#include <hip/hip_runtime.h>

typedef __attribute__((ext_vector_type(8))) _Float16 f16x8;
typedef __attribute__((ext_vector_type(2))) __fp16   fp16x2;  // cvt_pkrtz return type
typedef __attribute__((ext_vector_type(4))) float    f32x4;

#define TT 16384
#define KD 1024
#define ND 3072
#define NE 16
#define ASZ (TT * KD)                   // 16777216 elements
#define WSZ (NE * ND * KD)              // 50331648 elements
#define NEED_WS ((size_t)(ASZ + WSZ) * 2)

#define BM 256
#define BN 256
#define BK 64
#define NSTEP (KD / BK)                 // 16
#define ROWB (BK * 2)                   // 128 B per LDS row (f16)

#define BAR() __builtin_amdgcn_s_barrier()
#define WAIT_VM(n) asm volatile("s_waitcnt vmcnt(" #n ")" ::: "memory")

// XOR swizzle: conflict-free ds_read_b128 column access on 128B rows (m201).
__device__ __forceinline__ int swz(int row, int kbyte) {
    return row * ROWB + (kbyte ^ ((row & 7) << 4));
}

__device__ __forceinline__ int find_expert(const void* cntp, int row0) {
    // JAX default config demotes int64 -> int32; detect which layout we got.
    const int* w = (const int*)cntp;
    int oddsum = 0;
    #pragma unroll
    for (int i = 1; i < 16; i += 2) oddsum |= w[i];
    int e = 0;
    long long cum = 0;
    if (oddsum == 0) {  // int64 counts
        const long long* c = (const long long*)cntp;
        #pragma unroll
        for (int i = 0; i < NE; ++i) { if ((long long)row0 >= cum) e = i; cum += c[i]; }
    } else {            // int32 counts
        #pragma unroll
        for (int i = 0; i < NE; ++i) { if ((long long)row0 >= cum) e = i; cum += w[i]; }
    }
    return e;
}

// Direct global->LDS DMA, 16B/lane. LDS dest = wave-uniform base + lane*16.
__device__ __forceinline__ void gl16(const void* g, void* l) {
    __builtin_amdgcn_global_load_lds(
        (const __attribute__((address_space(1))) unsigned int*)g,
        (__attribute__((address_space(3))) unsigned int*)l, 16, 0, 0);
}

// ---------------- pre-pass: fp32 -> f16 for A and W ----------------
__global__ __launch_bounds__(256) void cvt_kernel(const float* __restrict__ A,
                                                  const float* __restrict__ W,
                                                  _Float16* __restrict__ dst) {
    size_t i = ((size_t)blockIdx.x * 256 + threadIdx.x) * 8;
    const float* src = (i < (size_t)ASZ) ? (A + i) : (W + (i - ASZ));
    f32x4 v0 = *(const f32x4*)src;
    f32x4 v1 = *(const f32x4*)(src + 4);
    f16x8 h;
    h[0] = (_Float16)v0[0]; h[1] = (_Float16)v0[1];
    h[2] = (_Float16)v0[2]; h[3] = (_Float16)v0[3];
    h[4] = (_Float16)v1[0]; h[5] = (_Float16)v1[1];
    h[6] = (_Float16)v1[2]; h[7] = (_Float16)v1[3];
    *(f16x8*)(dst + i) = h;
}

// ---------------- main GEMM: f16 inputs, global_load_lds staging,
// counted-vmcnt double-buffer (T4), XOR swizzle via pre-swizzled source ----
__launch_bounds__(512, 2)
__global__ void gemm16(const _Float16* __restrict__ A16,
                       const void* __restrict__ cnt,
                       const _Float16* __restrict__ W16,
                       const float* __restrict__ bias,
                       float* __restrict__ Y) {
    // [buf][A/B][256 rows x 128 B] = 128 KiB
    __shared__ __align__(16) char lds[2][2][BM * ROWB];

    // T1: bijective XCD-aware swizzle (768 % 8 == 0)
    const int nwg = gridDim.x;
    const int bid0 = blockIdx.x;
    const int wgid = (bid0 & 7) * (nwg >> 3) + (bid0 >> 3);

    const int mt = wgid / (ND / BN);
    const int nt = wgid % (ND / BN);
    const int row0 = mt * BM;
    const int col0 = nt * BN;

    const int e = find_expert(cnt, row0);
    const _Float16* We = W16 + (size_t)e * ND * KD;

    const int tid = threadIdx.x;
    const int l = tid & 63;
    const int w = tid >> 6;   // wave 0..7
    const int wr = w >> 2;    // 0..1 (M half, 128 rows)
    const int wc = w & 3;     // 0..3 (N quarter, 64 cols)
    const int lr = l & 15;
    const int lk = l >> 4;

    // Staging (per wave): 4 gl16 for A rows [w*32, w*32+32), 4 for B.
    // Each gl16: 8 rows x 128 B. LDS dest linear; SOURCE pre-swizzled so the
    // read-side swz() sees conflict-free data (rule #21: both-sides).
    // Lane l covers LDS slot (row = 8i + (l>>3), byte = (l&7)*16); source byte
    // within the 128-B k-slice = ((l&7)*16) ^ ((l>>3)<<4)   [row&7 == l>>3].
    const int laneoff = ((l & 7) * 16) ^ ((l >> 3) << 4);
    const char* gA = (const char*)A16 +
                     (size_t)(row0 + w * 32 + (l >> 3)) * (KD * 2) + laneoff;
    const char* gB = (const char*)We +
                     (size_t)(col0 + w * 32 + (l >> 3)) * (KD * 2) + laneoff;

    auto issue = [&](int t, int buf) {   // 8 gl16 per thread-wave, 1 KB each
        const char* a = gA + t * 128;
        const char* b = gB + t * 128;
        char* la = &lds[buf][0][w * 4096];
        char* lb = &lds[buf][1][w * 4096];
        #pragma unroll
        for (int i = 0; i < 4; ++i) {
            gl16(a + i * (8 * KD * 2), la + i * 1024);
            gl16(b + i * (8 * KD * 2), lb + i * 1024);
        }
    };

    f32x4 acc[8][4] = {};   // per-wave 128x64 output

    auto compute = [&](const char* As, const char* Bs) {
        #pragma unroll
        for (int kk = 0; kk < 2; ++kk) {          // two K=32 sub-steps
            f16x8 af[8], bf[4];
            #pragma unroll
            for (int m = 0; m < 8; ++m) {
                int r = wr * 128 + m * 16 + lr;
                af[m] = *(const f16x8*)&As[swz(r, kk * 64 + lk * 16)];
            }
            #pragma unroll
            for (int n = 0; n < 4; ++n) {
                int r = wc * 64 + n * 16 + lr;
                bf[n] = *(const f16x8*)&Bs[swz(r, kk * 64 + lk * 16)];
            }
            __builtin_amdgcn_s_setprio(1);
            #pragma unroll
            for (int m = 0; m < 8; ++m)
                #pragma unroll
                for (int n = 0; n < 4; ++n)
                    acc[m][n] = __builtin_amdgcn_mfma_f32_16x16x32_f16(
                        af[m], bf[n], acc[m][n], 0, 0, 0);
            __builtin_amdgcn_s_setprio(0);
        }
    };

    // Prologue: tiles 0 and 1 in flight; wait only for tile 0 (vmcnt counted).
    issue(0, 0);
    issue(1, 1);
    WAIT_VM(8);
    BAR();

    for (int t = 0; t < NSTEP; ++t) {
        const int buf = t & 1;
        compute(lds[buf][0], lds[buf][1]);
        BAR();                               // all waves done reading buf
        if (t + 2 < NSTEP) {
            issue(t + 2, buf);               // refill freed buffer
            WAIT_VM(8);                      // t+1's loads done; t+2's in flight
            BAR();
        } else if (t + 1 < NSTEP) {
            WAIT_VM(0);                      // final tile: one-time drain
            BAR();
        }
    }

    // Epilogue: C/D layout col = lane&15, row = (lane>>4)*4 + j
    const int cb = col0 + wc * 64;
    const int rb0_ = row0 + wr * 128;
    float bv[4];
    #pragma unroll
    for (int n = 0; n < 4; ++n) bv[n] = bias[(size_t)e * ND + cb + n * 16 + lr];
    #pragma unroll
    for (int m = 0; m < 8; ++m) {
        #pragma unroll
        for (int j = 0; j < 4; ++j) {
            int r = rb0_ + m * 16 + lk * 4 + j;
            float* yp = Y + (size_t)r * ND + cb + lr;
            #pragma unroll
            for (int n = 0; n < 4; ++n)
                yp[n * 16] = acc[m][n][j] + bv[n];
        }
    }
}

// ---------------- fallback (R3 kernel, known-good 222 us) if ws too small ---
__launch_bounds__(512, 2)
__global__ void fallback_gemm(const float* __restrict__ A,
                              const void* __restrict__ cnt,
                              const float* __restrict__ W,
                              const float* __restrict__ bias,
                              float* __restrict__ Y) {
    __shared__ __align__(16) char ldsbuf[2][2][BM * ROWB];

    const int nwg = gridDim.x;
    const int bid0 = blockIdx.x;
    const int wgid = (bid0 & 7) * (nwg >> 3) + (bid0 >> 3);

    const int mt = wgid / (ND / BN);
    const int nt = wgid % (ND / BN);
    const int row0 = mt * BM;
    const int col0 = nt * BN;

    const int e = find_expert(cnt, row0);
    const float* We = W + (size_t)e * ND * KD;

    const int tid = threadIdx.x;
    const int lane = tid & 63;
    const int w = tid >> 6;
    const int wr = w >> 2;
    const int wc = w & 3;
    const int lr = lane & 15;
    const int lk = lane >> 4;

    int soff[4];
    size_t aoff[4], boff[4];
    #pragma unroll
    for (int c = 0; c < 4; ++c) {
        int q = c * 512 + tid;
        int r = q >> 3;
        int kb = (q & 7) * 8;
        soff[c] = swz(r, kb * 2);
        aoff[c] = (size_t)(row0 + r) * KD + kb;
        boff[c] = (size_t)(col0 + r) * KD + kb;
    }

    f32x4 ra[4][2], rb[4][2];

    auto load_regs = [&](int ks) {
        const int k0 = ks * BK;
        #pragma unroll
        for (int c = 0; c < 4; ++c) {
            const float* ap = A + aoff[c] + k0;
            ra[c][0] = *(const f32x4*)ap;
            ra[c][1] = *(const f32x4*)(ap + 4);
            const float* bp = We + boff[c] + k0;
            rb[c][0] = *(const f32x4*)bp;
            rb[c][1] = *(const f32x4*)(bp + 4);
        }
    };

    auto write_lds = [&](int buf) {
        #pragma unroll
        for (int c = 0; c < 4; ++c) {
            union { f16x8 v; fp16x2 h[4]; } ua, ub;
            ua.h[0] = __builtin_amdgcn_cvt_pkrtz(ra[c][0][0], ra[c][0][1]);
            ua.h[1] = __builtin_amdgcn_cvt_pkrtz(ra[c][0][2], ra[c][0][3]);
            ua.h[2] = __builtin_amdgcn_cvt_pkrtz(ra[c][1][0], ra[c][1][1]);
            ua.h[3] = __builtin_amdgcn_cvt_pkrtz(ra[c][1][2], ra[c][1][3]);
            ub.h[0] = __builtin_amdgcn_cvt_pkrtz(rb[c][0][0], rb[c][0][1]);
            ub.h[1] = __builtin_amdgcn_cvt_pkrtz(rb[c][0][2], rb[c][0][3]);
            ub.h[2] = __builtin_amdgcn_cvt_pkrtz(rb[c][1][0], rb[c][1][1]);
            ub.h[3] = __builtin_amdgcn_cvt_pkrtz(rb[c][1][2], rb[c][1][3]);
            *(f16x8*)&ldsbuf[buf][0][soff[c]] = ua.v;
            *(f16x8*)&ldsbuf[buf][1][soff[c]] = ub.v;
        }
    };

    f32x4 acc[8][4] = {};

    auto compute = [&](const char* As, const char* Bs) {
        #pragma unroll
        for (int kk = 0; kk < 2; ++kk) {
            f16x8 af[8], bf[4];
            #pragma unroll
            for (int m = 0; m < 8; ++m) {
                int r = wr * 128 + m * 16 + lr;
                af[m] = *(const f16x8*)&As[swz(r, kk * 64 + lk * 16)];
            }
            #pragma unroll
            for (int n = 0; n < 4; ++n) {
                int r = wc * 64 + n * 16 + lr;
                bf[n] = *(const f16x8*)&Bs[swz(r, kk * 64 + lk * 16)];
            }
            #pragma unroll
            for (int m = 0; m < 8; ++m)
                #pragma unroll
                for (int n = 0; n < 4; ++n)
                    acc[m][n] = __builtin_amdgcn_mfma_f32_16x16x32_f16(
                        af[m], bf[n], acc[m][n], 0, 0, 0);
        }
    };

    load_regs(0);
    write_lds(0);
    __syncthreads();

    for (int t = 0; t < NSTEP; ++t) {
        const int buf = t & 1;
        if (t + 1 < NSTEP) load_regs(t + 1);
        compute(ldsbuf[buf][0], ldsbuf[buf][1]);
        __syncthreads();
        if (t + 1 < NSTEP) write_lds(buf ^ 1);
        __syncthreads();
    }

    const int cb = col0 + wc * 64;
    const int rb0_ = row0 + wr * 128;
    float bv[4];
    #pragma unroll
    for (int n = 0; n < 4; ++n) bv[n] = bias[(size_t)e * ND + cb + n * 16 + lr];
    #pragma unroll
    for (int m = 0; m < 8; ++m) {
        #pragma unroll
        for (int j = 0; j < 4; ++j) {
            int r = rb0_ + m * 16 + lk * 4 + j;
            float* yp = Y + (size_t)r * ND + cb + lr;
            #pragma unroll
            for (int n = 0; n < 4; ++n)
                yp[n * 16] = acc[m][n][j] + bv[n];
        }
    }
}

extern "C" void kernel_launch(void* const* d_in, const int* in_sizes, int n_in,
                              void* d_out, int out_size, void* d_ws, size_t ws_size,
                              hipStream_t stream) {
    const float* inp  = (const float*)d_in[0];
    const void*  cnt  = d_in[1];               // int32 or int64, detected in-kernel
    const float* wgt  = (const float*)d_in[2];
    const float* bias = (const float*)d_in[3];
    float* out = (float*)d_out;

    dim3 grid((TT / BM) * (ND / BN));          // 64 * 12 = 768 blocks
    dim3 block(512);

    if (ws_size >= NEED_WS) {
        _Float16* ws16 = (_Float16*)d_ws;
        // (ASZ+WSZ)/8 elements-per-thread / 256 threads = 32768 blocks
        cvt_kernel<<<dim3((ASZ + WSZ) / (8 * 256)), dim3(256), 0, stream>>>(inp, wgt, ws16);
        gemm16<<<grid, block, 0, stream>>>(ws16, cnt, ws16 + ASZ, bias, out);
    } else {
        fallback_gemm<<<grid, block, 0, stream>>>(inp, cnt, wgt, bias, out);
    }
}